// Round 5
// baseline (66.534 us; speedup 1.0000x reference)
//
#include <hip/hip_runtime.h>
#include <math.h>

#define B 8
#define G 64
#define S 256
#define DIM 41
#define ET 128
#define H 8
#define EK 16
#define NH 127
#define HD (H*DIM)   // 328
#define VTROW 260    // LDS row stride for vT[d][s] (260 % 32 == 4 -> bank spread)

// ---------------- K1 "prep": kproj->kpT4, qproj, embitsT, value-transpose ----------------
// grid 1800 x 256:
//   [0,1024): kproj, 2 rows each; [1024,1280): qproj, 2 rows each;
//   [1280,1792): embitsT per (b,g) (mask staged via LDS, coalesced);
//   [1792,1800): value transpose per b -> vTg[b][d][s]
__global__ __launch_bounds__(256) void prep_kernel(const float* __restrict__ key,
                                                   const float* __restrict__ Wk,
                                                   const float* __restrict__ bk,
                                                   const float* __restrict__ query,
                                                   const float* __restrict__ Wq,
                                                   const float* __restrict__ bq,
                                                   const float* __restrict__ mask,
                                                   const float* __restrict__ qt,
                                                   const float* __restrict__ tt,
                                                   const float* __restrict__ stride_in,
                                                   const float* __restrict__ Wr,
                                                   const float* __restrict__ br,
                                                   const float* __restrict__ value,
                                                   float* __restrict__ kpT,
                                                   float* __restrict__ qp,
                                                   unsigned int* __restrict__ embitsT,
                                                   float* __restrict__ vTg) {
    __shared__ float smem[5248 + 64];   // 128 mask rows (128*41) + strd
    const int bid = blockIdx.x;
    const int tid = threadIdx.x;

    if (bid < 1024) {
        // ---- kproj: rows bid*2, bid*2+1 -> kpT float layout b*32768 + (j>>2)*1024 + s*4 + (j&3)
        float* k0 = smem;
        float* k1 = smem + 48;
        const int half = tid >> 7;
        const int j = tid & 127;
        const int row = bid * 2 + half;
        if (j < DIM) (half ? k1 : k0)[j] = key[row * DIM + j];
        __syncthreads();
        const float* kr = half ? k1 : k0;
        float acc = bk[j];
#pragma unroll
        for (int i = 0; i < DIM; ++i) acc = fmaf(kr[i], Wk[i * ET + j], acc);
        const int b = row >> 8, s = row & 255;
        kpT[b * 32768 + (j >> 2) * 1024 + s * 4 + (j & 3)] = acc;
    } else if (bid < 1280) {
        // ---- qproj
        float* qlds = smem;             // [2][128]
        const int base = (bid - 1024) * 2;
        qlds[tid] = query[base * ET + tid];
        __syncthreads();
        const int half = tid >> 7;
        const int j = tid & 127;
        const float* qr = qlds + half * 128;
        float a0 = 0.f, a1 = 0.f, a2 = 0.f, a3 = 0.f;
#pragma unroll 8
        for (int i = 0; i < ET; i += 4) {
            a0 = fmaf(qr[i + 0], Wq[(i + 0) * ET + j], a0);
            a1 = fmaf(qr[i + 1], Wq[(i + 1) * ET + j], a1);
            a2 = fmaf(qr[i + 2], Wq[(i + 2) * ET + j], a2);
            a3 = fmaf(qr[i + 3], Wq[(i + 3) * ET + j], a3);
        }
        qp[(base + half) * ET + j] = bq[j] + ((a0 + a1) + (a2 + a3));
    } else if (bid < 1792) {
        // ---- embitsT per (b,g): bit(s,d) = window & mask, d-major words:
        // embitsT[bg*328 + d*8 + (s>>5)], bit (s&31)
        float* mlds = smem;
        float* strd = smem + 5248;
        const int bg = bid - 1280;
        const int b = bg >> 6, g = bg & 63;
        if (tid < DIM) {
            float a = br[tid];
            for (int i = 0; i < DIM; ++i) a = fmaf(stride_in[i], Wr[i * DIM + tid], a);
            strd[tid] = 1.0f / (1.0f + expf(-a));
        }
        __syncthreads();
        const float qtg = qt[g];
        for (int rr = 0; rr < 2; ++rr) {
            for (int idx = tid; idx < 5248; idx += 256)
                mlds[idx] = mask[(size_t)b * S * DIM + rr * 5248 + idx];
            __syncthreads();
            if (tid < 128) {
                const int s = rr * 128 + tid;
                const float t = tt[b * S + s];
                const int wv = tid >> 6;
                const int w = rr * 2 + wv;
                unsigned int* op = embitsT + (size_t)bg * (DIM * 8) + w * 2;
#pragma unroll
                for (int d = 0; d < DIM; ++d) {
                    const float sd = strd[d];
                    const int ok = (t >= qtg - sd) & (t <= qtg + sd) & (mlds[tid * DIM + d] != 0.0f);
                    const unsigned long long bal = __ballot(ok);
                    if ((tid & 63) == 0) {
                        op[d * 8 + 0] = (unsigned int)bal;
                        op[d * 8 + 1] = (unsigned int)(bal >> 32);
                    }
                }
            }
            __syncthreads();
        }
    } else {
        // ---- value transpose: vTg[b][d][s] = value[b][s][d]; writes coalesced
        const int b = bid - 1792;
        for (int idx = tid; idx < DIM * S; idx += 256) {
            const int d = idx >> 8, s = idx & 255;
            vTg[(size_t)b * (DIM * S) + idx] = value[(size_t)b * S * DIM + s * DIM + d];
        }
    }
}

// ---------------- K2 "main": scores + softmax + masked PV + outproj, per (b,g) ----------------
__global__ __launch_bounds__(512) void main_kernel(const float* __restrict__ kpT,
                                                   const float* __restrict__ qp,
                                                   const unsigned int* __restrict__ embitsT,
                                                   const float* __restrict__ vTg,
                                                   const float* __restrict__ Wo,
                                                   const float* __restrict__ bo,
                                                   float* __restrict__ out) {
    __shared__ float vT[DIM * VTROW];  // [d][s], row stride 260
    __shared__ float se[H][S];         // scores then exp(score-M)
    __shared__ float qv[ET];
    __shared__ float Mb[H];
    __shared__ float xrow[HD];
    __shared__ float po[4][128];

    const int bg = blockIdx.x;
    const int b = bg >> 6;
    const int tid = threadIdx.x;

    // (h,d) mapping for weighted phase; preload bit words early
    const int hd_h = tid / DIM;
    const int hd_d = tid - hd_h * DIM;
    unsigned int ebw0 = 0, ebw1 = 0, ebw2 = 0, ebw3 = 0, ebw4 = 0, ebw5 = 0, ebw6 = 0, ebw7 = 0;
    if (tid < HD) {
        const uint4* p = reinterpret_cast<const uint4*>(embitsT + (size_t)bg * (DIM * 8) + hd_d * 8);
        const uint4 e0 = p[0], e1 = p[1];
        ebw0 = e0.x; ebw1 = e0.y; ebw2 = e0.z; ebw3 = e0.w;
        ebw4 = e1.x; ebw5 = e1.y; ebw6 = e1.z; ebw7 = e1.w;
    }

    if (tid < ET) qv[tid] = qp[(size_t)bg * ET + tid];
    // stage vT: global [d][s] (coalesced) -> LDS rows of stride 260 (conflict-free writes)
    for (int idx = tid; idx < DIM * S; idx += 512) {
        const int d = idx >> 8, s = idx & 255;
        vT[d * VTROW + s] = vTg[(size_t)b * (DIM * S) + idx];
    }
    __syncthreads();

    // scores: s = tid (256 threads), 8 heads in registers
    float sc8[H];
    if (tid < S) {
        const float4* kb = reinterpret_cast<const float4*>(kpT) + (size_t)b * 8192 + tid;
#pragma unroll
        for (int h = 0; h < H; ++h) {
            float a = 0.f;
#pragma unroll
            for (int e4 = 0; e4 < 4; ++e4) {
                const float4 kv = kb[(h * 4 + e4) * 256];
                a = fmaf(qv[h * EK + e4 * 4 + 0], kv.x, a);
                a = fmaf(qv[h * EK + e4 * 4 + 1], kv.y, a);
                a = fmaf(qv[h * EK + e4 * 4 + 2], kv.z, a);
                a = fmaf(qv[h * EK + e4 * 4 + 3], kv.w, a);
            }
            sc8[h] = a * 0.25f;        // 1/sqrt(EK)
            se[h][tid] = sc8[h];
        }
    }
    __syncthreads();

    // per-head max: threads 0..255, h = tid>>5, j = tid&31
    if (tid < S) {
        const int h = tid >> 5, j = tid & 31;
        float m = se[h][j];
#pragma unroll
        for (int k = 1; k < 8; ++k) m = fmaxf(m, se[h][j + 32 * k]);
#pragma unroll
        for (int off = 16; off; off >>= 1) m = fmaxf(m, __shfl_xor(m, off, 32));
        if (j == 0) Mb[h] = m;
    }
    __syncthreads();

    // exp (from registers)
    if (tid < S) {
#pragma unroll
        for (int h = 0; h < H; ++h) se[h][tid] = __expf(sc8[h] - Mb[h]);
    }
    __syncthreads();

    // weighted phase: thread (h,d); quad-s iterations, b128 reads of e-row and vT-row
    if (tid < HD) {
        const int h = hd_h, d = hd_d;
        const float* erow = &se[h][0];
        const float* vrow = &vT[d * VTROW];
        const unsigned int ws[8] = {ebw0, ebw1, ebw2, ebw3, ebw4, ebw5, ebw6, ebw7};
        float Ssum = 0.f, acc = 0.f;
#pragma unroll
        for (int k = 0; k < 8; ++k) {
            const unsigned int wv = ws[k];
#pragma unroll
            for (int q = 0; q < 8; ++q) {
                const int s0 = k * 32 + q * 4;
                const float4 e4 = *reinterpret_cast<const float4*>(&erow[s0]);
                const float4 v4 = *reinterpret_cast<const float4*>(&vrow[s0]);
                const unsigned sh = q * 4;
                const float em0 = ((wv >> (sh + 0)) & 1u) ? e4.x : 0.f;
                const float em1 = ((wv >> (sh + 1)) & 1u) ? e4.y : 0.f;
                const float em2 = ((wv >> (sh + 2)) & 1u) ? e4.z : 0.f;
                const float em3 = ((wv >> (sh + 3)) & 1u) ? e4.w : 0.f;
                Ssum += em0 + em1 + em2 + em3;
                acc = fmaf(em0, v4.x, acc);
                acc = fmaf(em1, v4.y, acc);
                acc = fmaf(em2, v4.z, acc);
                acc = fmaf(em3, v4.w, acc);
            }
        }
        float r;
        if (Ssum != 0.f) {
            r = acc / Ssum;
        } else {
            // all-masked column: uniform softmax -> column mean of value
            float vs = 0.f;
            for (int s2 = 0; s2 < S; ++s2) vs += vrow[s2];
            r = vs * (1.0f / S);
        }
        xrow[tid] = r;
    }
    __syncthreads();

    // out-proj: 4 i-chunks of 82, lanes n = tid&127
    {
        const int n = tid & 127, c = tid >> 7;
        if (n < NH) {
            const int i0 = c * 82;
            float a0 = 0.f, a1 = 0.f;
#pragma unroll 2
            for (int i = i0; i < i0 + 82; i += 2) {
                a0 = fmaf(xrow[i],     Wo[(size_t)i * NH + n],       a0);
                a1 = fmaf(xrow[i + 1], Wo[(size_t)(i + 1) * NH + n], a1);
            }
            po[c][n] = a0 + a1;
        }
    }
    __syncthreads();
    if (tid < NH)
        out[(size_t)bg * NH + tid] = bo[tid] + ((po[0][tid] + po[1][tid]) + (po[2][tid] + po[3][tid]));
}

extern "C" void kernel_launch(void* const* d_in, const int* in_sizes, int n_in,
                              void* d_out, int out_size, void* d_ws, size_t ws_size,
                              hipStream_t stream) {
    const float* query     = (const float*)d_in[0];
    const float* key       = (const float*)d_in[1];
    const float* value     = (const float*)d_in[2];
    const float* mask      = (const float*)d_in[3];
    const float* qt        = (const float*)d_in[4];
    const float* tt        = (const float*)d_in[5];
    const float* stride_in = (const float*)d_in[6];
    const float* Wq        = (const float*)d_in[7];
    const float* bq        = (const float*)d_in[8];
    const float* Wk        = (const float*)d_in[9];
    const float* bk        = (const float*)d_in[10];
    const float* Wo        = (const float*)d_in[11];
    const float* bo        = (const float*)d_in[12];
    const float* Wr        = (const float*)d_in[13];
    const float* br        = (const float*)d_in[14];
    float* out = (float*)d_out;

    float* kpT = (float*)d_ws;                                         // 262144 f32
    float* qp = kpT + (size_t)B * H * 4 * S * 4;                       // 65536 f32
    unsigned int* embitsT = (unsigned int*)(qp + (size_t)B * G * ET);  // B*G*DIM*8 u32
    float* vTg = (float*)(embitsT + (size_t)B * G * DIM * 8);          // B*DIM*S f32

    prep_kernel<<<1800, 256, 0, stream>>>(key, Wk, bk, query, Wq, bq, mask, qt, tt,
                                          stride_in, Wr, br, value, kpT, qp, embitsT, vTg);
    main_kernel<<<B * G, 512, 0, stream>>>(kpT, qp, embitsT, vTg, Wo, bo, out);
}

// Round 7
// 52.413 us; speedup vs baseline: 1.2694x; 1.2694x over previous
//
#include <hip/hip_runtime.h>
#include <math.h>

#define B 8
#define G 64
#define S 256
#define DIM 41
#define ET 128
#define H 8
#define EK 16
#define NH 127
#define HD (H*DIM)   // 328
#define VROW 44      // padded value row (16B-aligned quads, zeros in pad)
#define SEROW 257    // padded se row

// ---------------- K1 "prep": kproj->kpT4, qproj, embitsT ----------------
// grid 1792 x 256 (proven r3 structure):
//   [0,1024): kproj, 2 rows each; [1024,1280): qproj, 2 rows each;
//   [1280,1792): embitsT per (b,g) (mask staged via LDS, coalesced)
__global__ __launch_bounds__(256) void prep_kernel(const float* __restrict__ key,
                                                   const float* __restrict__ Wk,
                                                   const float* __restrict__ bk,
                                                   const float* __restrict__ query,
                                                   const float* __restrict__ Wq,
                                                   const float* __restrict__ bq,
                                                   const float* __restrict__ mask,
                                                   const float* __restrict__ qt,
                                                   const float* __restrict__ tt,
                                                   const float* __restrict__ stride_in,
                                                   const float* __restrict__ Wr,
                                                   const float* __restrict__ br,
                                                   float* __restrict__ kpT,
                                                   float* __restrict__ qp,
                                                   unsigned int* __restrict__ embitsT) {
    __shared__ float smem[5248 + 64];   // 128 mask rows (128*41) + strd
    const int bid = blockIdx.x;
    const int tid = threadIdx.x;

    if (bid < 1024) {
        // ---- kproj: rows bid*2, bid*2+1 -> kpT float layout b*32768 + (j>>2)*1024 + s*4 + (j&3)
        float* k0 = smem;
        float* k1 = smem + 48;
        const int half = tid >> 7;
        const int j = tid & 127;
        const int row = bid * 2 + half;
        if (j < DIM) (half ? k1 : k0)[j] = key[row * DIM + j];
        __syncthreads();
        const float* kr = half ? k1 : k0;
        float acc = bk[j];
#pragma unroll
        for (int i = 0; i < DIM; ++i) acc = fmaf(kr[i], Wk[i * ET + j], acc);
        const int b = row >> 8, s = row & 255;
        kpT[b * 32768 + (j >> 2) * 1024 + s * 4 + (j & 3)] = acc;
    } else if (bid < 1280) {
        // ---- qproj
        float* qlds = smem;             // [2][128]
        const int base = (bid - 1024) * 2;
        qlds[tid] = query[base * ET + tid];
        __syncthreads();
        const int half = tid >> 7;
        const int j = tid & 127;
        const float* qr = qlds + half * 128;
        float a0 = 0.f, a1 = 0.f, a2 = 0.f, a3 = 0.f;
#pragma unroll 8
        for (int i = 0; i < ET; i += 4) {
            a0 = fmaf(qr[i + 0], Wq[(i + 0) * ET + j], a0);
            a1 = fmaf(qr[i + 1], Wq[(i + 1) * ET + j], a1);
            a2 = fmaf(qr[i + 2], Wq[(i + 2) * ET + j], a2);
            a3 = fmaf(qr[i + 3], Wq[(i + 3) * ET + j], a3);
        }
        qp[(base + half) * ET + j] = bq[j] + ((a0 + a1) + (a2 + a3));
    } else {
        // ---- embitsT per (b,g): bit(s,d) = window & mask, d-major words:
        // embitsT[bg*328 + d*8 + (s>>5)], bit (s&31)
        float* mlds = smem;
        float* strd = smem + 5248;
        const int bg = bid - 1280;
        const int b = bg >> 6, g = bg & 63;
        if (tid < DIM) {
            float a = br[tid];
            for (int i = 0; i < DIM; ++i) a = fmaf(stride_in[i], Wr[i * DIM + tid], a);
            strd[tid] = 1.0f / (1.0f + expf(-a));
        }
        __syncthreads();
        const float qtg = qt[g];
        for (int rr = 0; rr < 2; ++rr) {
            for (int idx = tid; idx < 5248; idx += 256)
                mlds[idx] = mask[(size_t)b * S * DIM + rr * 5248 + idx];
            __syncthreads();
            if (tid < 128) {
                const int s = rr * 128 + tid;
                const float t = tt[b * S + s];
                const int wv = tid >> 6;
                const int w = rr * 2 + wv;
                unsigned int* op = embitsT + (size_t)bg * (DIM * 8) + w * 2;
#pragma unroll
                for (int d = 0; d < DIM; ++d) {
                    const float sd = strd[d];
                    const int ok = (t >= qtg - sd) & (t <= qtg + sd) & (mlds[tid * DIM + d] != 0.0f);
                    const unsigned long long bal = __ballot(ok);
                    if ((tid & 63) == 0) {
                        op[d * 8 + 0] = (unsigned int)bal;
                        op[d * 8 + 1] = (unsigned int)(bal >> 32);
                    }
                }
            }
            __syncthreads();
        }
    }
}

// ---------------- K2 "main": scores + softmax + masked PV + outproj, per (b,g) ----------------
// 384 threads (6 waves). Weighted phase: thread = (ch, h, dq) with 88 threads per s-chunk.
__global__ __launch_bounds__(384) void main_kernel(const float* __restrict__ kpT,
                                                   const float* __restrict__ qp,
                                                   const unsigned int* __restrict__ embitsT,
                                                   const float* __restrict__ value,
                                                   const float* __restrict__ Wo,
                                                   const float* __restrict__ bo,
                                                   float* __restrict__ out) {
    __shared__ float vlds[S * VROW];    // [s][44], 45056 B
    __shared__ float se[H * SEROW];     // scores then e, padded rows
    __shared__ float qv[ET];
    __shared__ float Mb[H];
    __shared__ float pS[4 * 352];       // partials per s-chunk, [ch][h*44+d]
    __shared__ float pA[4 * 352];
    __shared__ float xrow[HD];
    __shared__ float po[3][128];

    const int bg = blockIdx.x;
    const int b = bg >> 6;
    const int tid = threadIdx.x;

    // weighted-phase mapping: tid = ch*88 + hh*11 + dq  (4 chunks x 8 heads x 11 quads = 352 active)
    const int ch = tid / 88;            // s-chunk (64 s each)
    const int r_ = tid - ch * 88;
    const int hh = r_ / 11;             // head 0..7
    const int dq = r_ - hh * 11;        // d-quad 0..10
    const bool wact = (tid < 352);
    unsigned int wA[4], wB[4];
    if (wact) {
        const unsigned int* eb = embitsT + (size_t)bg * (DIM * 8);
#pragma unroll
        for (int j = 0; j < 4; ++j) {
            const int d = dq * 4 + j;
            wA[j] = (d < DIM) ? eb[d * 8 + ch * 2 + 0] : 0u;
            wB[j] = (d < DIM) ? eb[d * 8 + ch * 2 + 1] : 0u;
        }
    }

    if (tid < ET) qv[tid] = qp[(size_t)bg * ET + tid];
    // stage value padded to VROW (zeros in pad)
    for (int q = tid; q < S * 11; q += 384) {
        const int s = q / 11, dqq = q - (q / 11) * 11;
        const float* vp = value + (size_t)b * S * DIM + s * DIM + dqq * 4;
        float4 t;
        if (dqq < 10) { t.x = vp[0]; t.y = vp[1]; t.z = vp[2]; t.w = vp[3]; }
        else          { t.x = vp[0]; t.y = 0.f;   t.z = 0.f;   t.w = 0.f;  }
        *reinterpret_cast<float4*>(&vlds[s * VROW + dqq * 4]) = t;
    }
    __syncthreads();

    // scores: s = tid (256 threads), 8 heads in registers (proven r3)
    float sc8[H];
    if (tid < S) {
        const float4* kb = reinterpret_cast<const float4*>(kpT) + (size_t)b * 8192 + tid;
#pragma unroll
        for (int h = 0; h < H; ++h) {
            float a = 0.f;
#pragma unroll
            for (int e4 = 0; e4 < 4; ++e4) {
                const float4 kv = kb[(h * 4 + e4) * 256];
                a = fmaf(qv[h * EK + e4 * 4 + 0], kv.x, a);
                a = fmaf(qv[h * EK + e4 * 4 + 1], kv.y, a);
                a = fmaf(qv[h * EK + e4 * 4 + 2], kv.z, a);
                a = fmaf(qv[h * EK + e4 * 4 + 3], kv.w, a);
            }
            sc8[h] = a * 0.25f;          // 1/sqrt(EK)
            se[h * SEROW + tid] = sc8[h];
        }
    }
    __syncthreads();

    // per-head max: threads 0..255, h = tid>>5, j = tid&31 (proven r3)
    if (tid < S) {
        const int h = tid >> 5, j = tid & 31;
        float m = se[h * SEROW + j];
#pragma unroll
        for (int k = 1; k < 8; ++k) m = fmaxf(m, se[h * SEROW + j + 32 * k]);
#pragma unroll
        for (int off = 16; off; off >>= 1) m = fmaxf(m, __shfl_xor(m, off, 32));
        if (j == 0) Mb[h] = m;
    }
    __syncthreads();

    // exp (from registers)
    if (tid < S) {
#pragma unroll
        for (int h = 0; h < H; ++h) se[h * SEROW + tid] = __expf(sc8[h] - Mb[h]);
    }
    __syncthreads();

    // weighted phase: per thread, 64 s for (1 head x 4 d)
    if (wact) {
        const int s0 = ch * 64;
        const float* er = &se[hh * SEROW];
        float aS0 = 0.f, aS1 = 0.f, aS2 = 0.f, aS3 = 0.f;
        float aA0 = 0.f, aA1 = 0.f, aA2 = 0.f, aA3 = 0.f;
#pragma unroll 8
        for (int i = 0; i < 32; ++i) {
            const int s = s0 + i;
            const float e = er[s];
            const float4 v4 = *reinterpret_cast<const float4*>(&vlds[s * VROW + dq * 4]);
            const float e0 = ((wA[0] >> i) & 1u) ? e : 0.f;
            const float e1 = ((wA[1] >> i) & 1u) ? e : 0.f;
            const float e2 = ((wA[2] >> i) & 1u) ? e : 0.f;
            const float e3 = ((wA[3] >> i) & 1u) ? e : 0.f;
            aS0 += e0; aA0 = fmaf(e0, v4.x, aA0);
            aS1 += e1; aA1 = fmaf(e1, v4.y, aA1);
            aS2 += e2; aA2 = fmaf(e2, v4.z, aA2);
            aS3 += e3; aA3 = fmaf(e3, v4.w, aA3);
        }
#pragma unroll 8
        for (int i = 0; i < 32; ++i) {
            const int s = s0 + 32 + i;
            const float e = er[s];
            const float4 v4 = *reinterpret_cast<const float4*>(&vlds[s * VROW + dq * 4]);
            const float e0 = ((wB[0] >> i) & 1u) ? e : 0.f;
            const float e1 = ((wB[1] >> i) & 1u) ? e : 0.f;
            const float e2 = ((wB[2] >> i) & 1u) ? e : 0.f;
            const float e3 = ((wB[3] >> i) & 1u) ? e : 0.f;
            aS0 += e0; aA0 = fmaf(e0, v4.x, aA0);
            aS1 += e1; aA1 = fmaf(e1, v4.y, aA1);
            aS2 += e2; aA2 = fmaf(e2, v4.z, aA2);
            aS3 += e3; aA3 = fmaf(e3, v4.w, aA3);
        }
        const int base = ch * 352 + hh * 44 + dq * 4;
        pS[base + 0] = aS0; pS[base + 1] = aS1; pS[base + 2] = aS2; pS[base + 3] = aS3;
        pA[base + 0] = aA0; pA[base + 1] = aA1; pA[base + 2] = aA2; pA[base + 3] = aA3;
    }
    __syncthreads();

    // final reduce over 4 chunks + normalize
    if (tid < HD) {
        const int h = tid / DIM, d = tid - h * DIM;
        const int o = h * 44 + d;
        const float Ss = (pS[o] + pS[352 + o]) + (pS[704 + o] + pS[1056 + o]);
        const float Aa = (pA[o] + pA[352 + o]) + (pA[704 + o] + pA[1056 + o]);
        float r;
        if (Ss != 0.f) {
            r = Aa / Ss;
        } else {
            // all-masked column: uniform softmax -> column mean of value (never taken in practice)
            float vs = 0.f;
            for (int s2 = 0; s2 < S; ++s2) vs += vlds[s2 * VROW + d];
            r = vs * (1.0f / S);
        }
        xrow[tid] = r;
    }
    __syncthreads();

    // out-proj: 3 i-chunks (110,110,108), lanes n = tid&127 (proven r4)
    {
        const int n = tid & 127, c = tid >> 7;
        const int i0 = c * 110, i1 = (c == 2) ? HD : (i0 + 110);
        if (n < NH) {
            float a0 = 0.f, a1 = 0.f;
            for (int i = i0; i < i1; i += 2) {
                a0 = fmaf(xrow[i],     Wo[(size_t)i * NH + n],       a0);
                a1 = fmaf(xrow[i + 1], Wo[(size_t)(i + 1) * NH + n], a1);
            }
            po[c][n] = a0 + a1;
        }
    }
    __syncthreads();
    if (tid < NH)
        out[(size_t)bg * NH + tid] = bo[tid] + ((po[0][tid] + po[1][tid]) + po[2][tid]);
}

extern "C" void kernel_launch(void* const* d_in, const int* in_sizes, int n_in,
                              void* d_out, int out_size, void* d_ws, size_t ws_size,
                              hipStream_t stream) {
    const float* query     = (const float*)d_in[0];
    const float* key       = (const float*)d_in[1];
    const float* value     = (const float*)d_in[2];
    const float* mask      = (const float*)d_in[3];
    const float* qt        = (const float*)d_in[4];
    const float* tt        = (const float*)d_in[5];
    const float* stride_in = (const float*)d_in[6];
    const float* Wq        = (const float*)d_in[7];
    const float* bq        = (const float*)d_in[8];
    const float* Wk        = (const float*)d_in[9];
    const float* bk        = (const float*)d_in[10];
    const float* Wo        = (const float*)d_in[11];
    const float* bo        = (const float*)d_in[12];
    const float* Wr        = (const float*)d_in[13];
    const float* br        = (const float*)d_in[14];
    float* out = (float*)d_out;

    float* kpT = (float*)d_ws;                                         // 262144 f32
    float* qp = kpT + (size_t)B * H * 4 * S * 4;                       // 65536 f32
    unsigned int* embitsT = (unsigned int*)(qp + (size_t)B * G * ET);  // B*G*DIM*8 u32

    prep_kernel<<<1792, 256, 0, stream>>>(key, Wk, bk, query, Wq, bq, mask, qt, tt,
                                          stride_in, Wr, br, kpT, qp, embitsT);
    main_kernel<<<B * G, 384, 0, stream>>>(kpT, qp, embitsT, value, Wo, bo, out);
}

// Round 8
// 39.914 us; speedup vs baseline: 1.6669x; 1.3131x over previous
//
#include <hip/hip_runtime.h>
#include <math.h>

#define B 8
#define G 64
#define S 256
#define DIM 41
#define ET 128
#define H 8
#define EK 16
#define NH 127
#define HD (H*DIM)   // 328
#define EROW 257     // padded e-row in attn LDS

// ---------------- K1 "prep": kproj->kpT4, qproj, embitsT (proven r3/r7 code) ----------------
// grid 1792 x 256:
//   [0,1024): kproj, 2 rows each; [1024,1280): qproj, 2 rows each;
//   [1280,1792): embitsT per (b,g) (mask staged via LDS, coalesced)
__global__ __launch_bounds__(256) void prep_kernel(const float* __restrict__ key,
                                                   const float* __restrict__ Wk,
                                                   const float* __restrict__ bk,
                                                   const float* __restrict__ query,
                                                   const float* __restrict__ Wq,
                                                   const float* __restrict__ bq,
                                                   const float* __restrict__ mask,
                                                   const float* __restrict__ qt,
                                                   const float* __restrict__ tt,
                                                   const float* __restrict__ stride_in,
                                                   const float* __restrict__ Wr,
                                                   const float* __restrict__ br,
                                                   float* __restrict__ kpT,
                                                   float* __restrict__ qp,
                                                   unsigned int* __restrict__ embitsT) {
    __shared__ float smem[5248 + 64];   // 128 mask rows (128*41) + strd
    const int bid = blockIdx.x;
    const int tid = threadIdx.x;

    if (bid < 1024) {
        // ---- kproj: rows bid*2, bid*2+1 -> kpT float layout b*32768 + (j>>2)*1024 + s*4 + (j&3)
        float* k0 = smem;
        float* k1 = smem + 48;
        const int half = tid >> 7;
        const int j = tid & 127;
        const int row = bid * 2 + half;
        if (j < DIM) (half ? k1 : k0)[j] = key[row * DIM + j];
        __syncthreads();
        const float* kr = half ? k1 : k0;
        float acc = bk[j];
#pragma unroll
        for (int i = 0; i < DIM; ++i) acc = fmaf(kr[i], Wk[i * ET + j], acc);
        const int b = row >> 8, s = row & 255;
        kpT[b * 32768 + (j >> 2) * 1024 + s * 4 + (j & 3)] = acc;
    } else if (bid < 1280) {
        // ---- qproj
        float* qlds = smem;             // [2][128]
        const int base = (bid - 1024) * 2;
        qlds[tid] = query[base * ET + tid];
        __syncthreads();
        const int half = tid >> 7;
        const int j = tid & 127;
        const float* qr = qlds + half * 128;
        float a0 = 0.f, a1 = 0.f, a2 = 0.f, a3 = 0.f;
#pragma unroll 8
        for (int i = 0; i < ET; i += 4) {
            a0 = fmaf(qr[i + 0], Wq[(i + 0) * ET + j], a0);
            a1 = fmaf(qr[i + 1], Wq[(i + 1) * ET + j], a1);
            a2 = fmaf(qr[i + 2], Wq[(i + 2) * ET + j], a2);
            a3 = fmaf(qr[i + 3], Wq[(i + 3) * ET + j], a3);
        }
        qp[(base + half) * ET + j] = bq[j] + ((a0 + a1) + (a2 + a3));
    } else {
        // ---- embitsT per (b,g): bit(s,d) = window & mask, d-major words:
        // embitsT[bg*328 + d*8 + (s>>5)], bit (s&31)
        float* mlds = smem;
        float* strd = smem + 5248;
        const int bg = bid - 1280;
        const int b = bg >> 6, g = bg & 63;
        if (tid < DIM) {
            float a = br[tid];
            for (int i = 0; i < DIM; ++i) a = fmaf(stride_in[i], Wr[i * DIM + tid], a);
            strd[tid] = 1.0f / (1.0f + expf(-a));
        }
        __syncthreads();
        const float qtg = qt[g];
        for (int rr = 0; rr < 2; ++rr) {
            for (int idx = tid; idx < 5248; idx += 256)
                mlds[idx] = mask[(size_t)b * S * DIM + rr * 5248 + idx];
            __syncthreads();
            if (tid < 128) {
                const int s = rr * 128 + tid;
                const float t = tt[b * S + s];
                const int wv = tid >> 6;
                const int w = rr * 2 + wv;
                unsigned int* op = embitsT + (size_t)bg * (DIM * 8) + w * 2;
#pragma unroll
                for (int d = 0; d < DIM; ++d) {
                    const float sd = strd[d];
                    const int ok = (t >= qtg - sd) & (t <= qtg + sd) & (mlds[tid * DIM + d] != 0.0f);
                    const unsigned long long bal = __ballot(ok);
                    if ((tid & 63) == 0) {
                        op[d * 8 + 0] = (unsigned int)bal;
                        op[d * 8 + 1] = (unsigned int)(bal >> 32);
                    }
                }
            }
            __syncthreads();
        }
    }
}

// ---------------- K2 "attn": scores + softmax + weighted sum for 4 heads ----------------
// grid B*G*2 = 1024 blocks x 256 threads. bg = bid>>1, head-quad = bid&1.
// Weighted phase is reduction-free: wave w = local head, lane = d.
__global__ __launch_bounds__(256) void attn_kernel(const float* __restrict__ kpT,
                                                   const float* __restrict__ qp,
                                                   const unsigned int* __restrict__ embitsT,
                                                   const float* __restrict__ value,
                                                   float* __restrict__ x) {
    __shared__ float elds[4 * EROW];    // e values per local head (padded rows)
    __shared__ float qlds[64];          // q fragment for these 4 heads
    __shared__ float Mb[4];

    const int bid = blockIdx.x;
    const int bg = bid >> 1;
    const int hq = bid & 1;             // head quad
    const int b = bg >> 6;
    const int tid = threadIdx.x;

    if (tid < 64) qlds[tid] = qp[(size_t)bg * ET + hq * 64 + tid];
    __syncthreads();

    // scores: thread = s, 4 local heads in registers
    float sc4[4];
    {
        const int s = tid;
        const float4* kb = reinterpret_cast<const float4*>(kpT) + (size_t)b * 8192 + s;
#pragma unroll
        for (int hl = 0; hl < 4; ++hl) {
            const int h = hq * 4 + hl;
            float a = 0.f;
#pragma unroll
            for (int e4 = 0; e4 < 4; ++e4) {
                const float4 kv = kb[(h * 4 + e4) * 256];
                a = fmaf(qlds[hl * EK + e4 * 4 + 0], kv.x, a);
                a = fmaf(qlds[hl * EK + e4 * 4 + 1], kv.y, a);
                a = fmaf(qlds[hl * EK + e4 * 4 + 2], kv.z, a);
                a = fmaf(qlds[hl * EK + e4 * 4 + 3], kv.w, a);
            }
            sc4[hl] = a * 0.25f;        // 1/sqrt(EK)
            elds[hl * EROW + s] = sc4[hl];
        }
    }
    __syncthreads();

    // per-head max: threads 0..127, hl = tid>>5, j = tid&31
    if (tid < 128) {
        const int hl = tid >> 5, j = tid & 31;
        float m = elds[hl * EROW + j];
#pragma unroll
        for (int k = 1; k < 8; ++k) m = fmaxf(m, elds[hl * EROW + j + 32 * k]);
#pragma unroll
        for (int off = 16; off; off >>= 1) m = fmaxf(m, __shfl_xor(m, off, 32));
        if (j == 0) Mb[hl] = m;
    }
    __syncthreads();

    // exp (from registers)
    {
        const int s = tid;
#pragma unroll
        for (int hl = 0; hl < 4; ++hl) elds[hl * EROW + s] = __expf(sc4[hl] - Mb[hl]);
    }
    __syncthreads();

    // weighted phase: wave w = local head, lane = d; no cross-lane reduction needed
    {
        const int w = tid >> 6;         // local head
        const int d = tid & 63;
        if (d < DIM) {
            // bits for this d (shared across heads)
            const uint4* bp = reinterpret_cast<const uint4*>(embitsT + (size_t)bg * (DIM * 8) + d * 8);
            const uint4 b0 = bp[0], b1 = bp[1];
            const unsigned int bw[8] = {b0.x, b0.y, b0.z, b0.w, b1.x, b1.y, b1.z, b1.w};
            const float* er = &elds[w * EROW];
            const float* vb = value + (size_t)b * S * DIM + d;
            float Ssum = 0.f, acc = 0.f;
#pragma unroll
            for (int k = 0; k < 8; ++k) {
                const unsigned int wv = bw[k];
#pragma unroll 8
                for (int i = 0; i < 32; ++i) {
                    const int s = k * 32 + i;
                    const float e = er[s];
                    const float v = vb[(size_t)s * DIM];
                    const float wgt = ((wv >> i) & 1u) ? e : 0.f;
                    Ssum += wgt;
                    acc = fmaf(wgt, v, acc);
                }
            }
            float r;
            if (Ssum != 0.f) {
                r = acc / Ssum;
            } else {
                // all-masked column: uniform softmax -> column mean (never taken in practice)
                float vs = 0.f;
                for (int s2 = 0; s2 < S; ++s2) vs += vb[(size_t)s2 * DIM];
                r = vs * (1.0f / S);
            }
            x[(size_t)bg * HD + (hq * 4 + w) * DIM + d] = r;
        }
    }
}

// ---------------- K3 "outproj": out[bg,:] = x[bg,:] @ Wo + bo ----------------
__global__ __launch_bounds__(128) void outproj_kernel(const float* __restrict__ x,
                                                      const float* __restrict__ Wo,
                                                      const float* __restrict__ bo,
                                                      float* __restrict__ out) {
    __shared__ float xr[HD];
    const int bg = blockIdx.x;
    const int tid = threadIdx.x;
    xr[tid] = x[(size_t)bg * HD + tid];
    xr[tid + 128] = x[(size_t)bg * HD + tid + 128];
    if (tid < HD - 256) xr[tid + 256] = x[(size_t)bg * HD + tid + 256];
    __syncthreads();
    if (tid < NH) {
        const int n = tid;
        float a0 = 0.f, a1 = 0.f, a2 = 0.f, a3 = 0.f;
#pragma unroll 2
        for (int i = 0; i < HD; i += 4) {   // HD = 328 = 4*82
            a0 = fmaf(xr[i + 0], Wo[(size_t)(i + 0) * NH + n], a0);
            a1 = fmaf(xr[i + 1], Wo[(size_t)(i + 1) * NH + n], a1);
            a2 = fmaf(xr[i + 2], Wo[(size_t)(i + 2) * NH + n], a2);
            a3 = fmaf(xr[i + 3], Wo[(size_t)(i + 3) * NH + n], a3);
        }
        out[(size_t)bg * NH + n] = bo[n] + ((a0 + a1) + (a2 + a3));
    }
}

extern "C" void kernel_launch(void* const* d_in, const int* in_sizes, int n_in,
                              void* d_out, int out_size, void* d_ws, size_t ws_size,
                              hipStream_t stream) {
    const float* query     = (const float*)d_in[0];
    const float* key       = (const float*)d_in[1];
    const float* value     = (const float*)d_in[2];
    const float* mask      = (const float*)d_in[3];
    const float* qt        = (const float*)d_in[4];
    const float* tt        = (const float*)d_in[5];
    const float* stride_in = (const float*)d_in[6];
    const float* Wq        = (const float*)d_in[7];
    const float* bq        = (const float*)d_in[8];
    const float* Wk        = (const float*)d_in[9];
    const float* bk        = (const float*)d_in[10];
    const float* Wo        = (const float*)d_in[11];
    const float* bo        = (const float*)d_in[12];
    const float* Wr        = (const float*)d_in[13];
    const float* br        = (const float*)d_in[14];
    float* out = (float*)d_out;

    float* kpT = (float*)d_ws;                                         // 262144 f32
    float* qp = kpT + (size_t)B * H * 4 * S * 4;                       // 65536 f32
    unsigned int* embitsT = (unsigned int*)(qp + (size_t)B * G * ET);  // B*G*DIM*8 u32
    float* x = (float*)(embitsT + (size_t)B * G * DIM * 8);            // B*G*HD f32

    prep_kernel<<<1792, 256, 0, stream>>>(key, Wk, bk, query, Wq, bq, mask, qt, tt,
                                          stride_in, Wr, br, kpT, qp, embitsT);
    attn_kernel<<<B * G * 2, 256, 0, stream>>>(kpT, qp, embitsT, value, x);
    outproj_kernel<<<B * G, 128, 0, stream>>>(x, Wo, bo, out);
}